// Round 1
// baseline (1942.355 us; speedup 1.0000x reference)
//
#include <hip/hip_runtime.h>
#include <cstddef>

#define TSEQ 48
#define TDEC 60

__device__ __forceinline__ float sigm(float x){ return 1.0f/(1.0f+__expf(-x)); }
__device__ __forceinline__ float tanhx(float x){ return 1.0f - 2.0f/(__expf(2.0f*x)+1.0f); }

__global__ __launch_bounds__(64)
void lstm_fused(const float* __restrict__ x,
                const float* __restrict__ w1i, const float* __restrict__ w1h, const float* __restrict__ b1,
                const float* __restrict__ w2i, const float* __restrict__ w2h, const float* __restrict__ b2,
                const float* __restrict__ w3i, const float* __restrict__ w3h, const float* __restrict__ b3,
                const float* __restrict__ w4i, const float* __restrict__ w4h, const float* __restrict__ b4,
                const float* __restrict__ w5i, const float* __restrict__ w5h, const float* __restrict__ b5,
                const float* __restrict__ w6i, const float* __restrict__ w6h, const float* __restrict__ b6,
                const float* __restrict__ fc1w, const float* __restrict__ fc1b,
                const float* __restrict__ fc2w, const float* __restrict__ fc2b,
                float* __restrict__ out)
{
    const int tid = threadIdx.x;           // 0..63
    const int b   = blockIdx.x * 64 + tid; // batch element

    // LSTM state for the two "wide" layers lives in LDS so the rolled unit-loops
    // can index it dynamically without spilling to scratch (rule: runtime-indexed
    // register arrays go to local memory). Layout [unit][tid]: lane-contiguous,
    // 2-way bank aliasing only (free). Thread-private columns -> no barriers.
    __shared__ float s_h1[32][64];
    __shared__ float s_c1[32][64];
    __shared__ float s_h2[8][64];
    __shared__ float s_c2[8][64];

    #pragma unroll
    for (int u=0; u<32; ++u){ s_h1[u][tid]=0.f; s_c1[u][tid]=0.f; }
    #pragma unroll
    for (int u=0; u<8; ++u){ s_h2[u][tid]=0.f; s_c2[u][tid]=0.f; }

    // tiny-layer state in registers (constant-indexed only)
    float h3=0.f, c3=0.f;
    float h4a=0.f,h4b=0.f,c4a=0.f,c4b=0.f;
    float h5a=0.f,h5b=0.f,c5a=0.f,c5b=0.f;
    float h6=0.f, c6=0.f;

    // fc1 accumulated incrementally as each decoder output h6(t) is produced
    float acc[32];
    #pragma unroll
    for (int u=0; u<32; ++u) acc[u]=fc1b[u];

    const float* xrow = x + (size_t)b * (TSEQ*8);

    for (int t=0; t<TDEC; ++t){
        float din;
        if (t < TSEQ){
            // ---- load x_t (32B, two aligned float4) ----
            const float4 xv0 = *reinterpret_cast<const float4*>(xrow + t*8);
            const float4 xv1 = *reinterpret_cast<const float4*>(xrow + t*8 + 4);
            float xt[8] = {xv0.x,xv0.y,xv0.z,xv0.w,xv1.x,xv1.y,xv1.z,xv1.w};

            // ---- e1: D=8, H=32 ----
            float hr[32];
            #pragma unroll
            for (int k=0;k<32;++k) hr[k]=s_h1[k][tid];

            for (int u=0; u<32; ++u){   // rolled; weights uniform -> s_load
                float gi=b1[u], gf=b1[32+u], gg=b1[64+u], go=b1[96+u];
                #pragma unroll
                for (int j=0;j<8;++j){
                    const float xvj=xt[j];
                    gi += w1i[u*8+j]*xvj;
                    gf += w1i[(32+u)*8+j]*xvj;
                    gg += w1i[(64+u)*8+j]*xvj;
                    go += w1i[(96+u)*8+j]*xvj;
                }
                #pragma unroll
                for (int k=0;k<32;++k){
                    const float hv=hr[k];
                    gi += w1h[u*32+k]*hv;
                    gf += w1h[(32+u)*32+k]*hv;
                    gg += w1h[(64+u)*32+k]*hv;
                    go += w1h[(96+u)*32+k]*hv;
                }
                const float c = sigm(gf)*s_c1[u][tid] + sigm(gi)*tanhx(gg);
                s_c1[u][tid] = c;
                s_h1[u][tid] = sigm(go)*tanhx(c);
            }

            // ---- e2: D=32, H=8 ----
            float h1n[32];
            #pragma unroll
            for (int k=0;k<32;++k) h1n[k]=s_h1[k][tid];
            float hr2[8];
            #pragma unroll
            for (int k=0;k<8;++k) hr2[k]=s_h2[k][tid];

            for (int u=0; u<8; ++u){
                float gi=b2[u], gf=b2[8+u], gg=b2[16+u], go=b2[24+u];
                #pragma unroll
                for (int j=0;j<32;++j){
                    const float xvj=h1n[j];
                    gi += w2i[u*32+j]*xvj;
                    gf += w2i[(8+u)*32+j]*xvj;
                    gg += w2i[(16+u)*32+j]*xvj;
                    go += w2i[(24+u)*32+j]*xvj;
                }
                #pragma unroll
                for (int k=0;k<8;++k){
                    const float hv=hr2[k];
                    gi += w2h[u*8+k]*hv;
                    gf += w2h[(8+u)*8+k]*hv;
                    gg += w2h[(16+u)*8+k]*hv;
                    go += w2h[(24+u)*8+k]*hv;
                }
                const float c = sigm(gf)*s_c2[u][tid] + sigm(gi)*tanhx(gg);
                s_c2[u][tid]=c;
                s_h2[u][tid]=sigm(go)*tanhx(c);
            }

            // ---- e3: D=8, H=1 (registers) ----
            float h2n[8];
            #pragma unroll
            for (int k=0;k<8;++k) h2n[k]=s_h2[k][tid];

            float gi=b3[0], gf=b3[1], gg=b3[2], go=b3[3];
            #pragma unroll
            for (int j=0;j<8;++j){
                gi += w3i[j]   *h2n[j];
                gf += w3i[8+j] *h2n[j];
                gg += w3i[16+j]*h2n[j];
                go += w3i[24+j]*h2n[j];
            }
            gi += w3h[0]*h3; gf += w3h[1]*h3; gg += w3h[2]*h3; go += w3h[3]*h3;
            c3 = sigm(gf)*c3 + sigm(gi)*tanhx(gg);
            h3 = sigm(go)*tanhx(c3);
            din = h3;
        } else {
            // x_aux = x[:, 36:48, 4]; dec time t in [48,60) -> x[b][t-12][4]
            din = xrow[(t-12)*8 + 4];
        }

        // ---- d1: D=1, H=2 ----
        {
            float g0=b4[0]+w4i[0]*din + w4h[0]*h4a +w4h[1]*h4b;
            float g1=b4[1]+w4i[1]*din + w4h[2]*h4a +w4h[3]*h4b;
            float g2=b4[2]+w4i[2]*din + w4h[4]*h4a +w4h[5]*h4b;
            float g3=b4[3]+w4i[3]*din + w4h[6]*h4a +w4h[7]*h4b;
            float g4=b4[4]+w4i[4]*din + w4h[8]*h4a +w4h[9]*h4b;
            float g5=b4[5]+w4i[5]*din + w4h[10]*h4a+w4h[11]*h4b;
            float g6=b4[6]+w4i[6]*din + w4h[12]*h4a+w4h[13]*h4b;
            float g7=b4[7]+w4i[7]*din + w4h[14]*h4a+w4h[15]*h4b;
            c4a = sigm(g2)*c4a + sigm(g0)*tanhx(g4);
            c4b = sigm(g3)*c4b + sigm(g1)*tanhx(g5);
            h4a = sigm(g6)*tanhx(c4a);
            h4b = sigm(g7)*tanhx(c4b);
        }
        // ---- d2: D=2, H=2 ----
        {
            float g0=b5[0]+w5i[0]*h4a +w5i[1]*h4b  + w5h[0]*h5a +w5h[1]*h5b;
            float g1=b5[1]+w5i[2]*h4a +w5i[3]*h4b  + w5h[2]*h5a +w5h[3]*h5b;
            float g2=b5[2]+w5i[4]*h4a +w5i[5]*h4b  + w5h[4]*h5a +w5h[5]*h5b;
            float g3=b5[3]+w5i[6]*h4a +w5i[7]*h4b  + w5h[6]*h5a +w5h[7]*h5b;
            float g4=b5[4]+w5i[8]*h4a +w5i[9]*h4b  + w5h[8]*h5a +w5h[9]*h5b;
            float g5=b5[5]+w5i[10]*h4a+w5i[11]*h4b + w5h[10]*h5a+w5h[11]*h5b;
            float g6=b5[6]+w5i[12]*h4a+w5i[13]*h4b + w5h[12]*h5a+w5h[13]*h5b;
            float g7=b5[7]+w5i[14]*h4a+w5i[15]*h4b + w5h[14]*h5a+w5h[15]*h5b;
            c5a = sigm(g2)*c5a + sigm(g0)*tanhx(g4);
            c5b = sigm(g3)*c5b + sigm(g1)*tanhx(g5);
            h5a = sigm(g6)*tanhx(c5a);
            h5b = sigm(g7)*tanhx(c5b);
        }
        // ---- d3: D=2, H=1 ----
        {
            float g0=b6[0]+w6i[0]*h5a+w6i[1]*h5b + w6h[0]*h6;
            float g1=b6[1]+w6i[2]*h5a+w6i[3]*h5b + w6h[1]*h6;
            float g2=b6[2]+w6i[4]*h5a+w6i[5]*h5b + w6h[2]*h6;
            float g3=b6[3]+w6i[6]*h5a+w6i[7]*h5b + w6h[3]*h6;
            c6 = sigm(g1)*c6 + sigm(g0)*tanhx(g2);
            h6 = sigm(g3)*tanhx(c6);
        }

        // ---- fc1 incremental accumulation: acc[u] += fc1_w[u][t] * out60[t] ----
        #pragma unroll
        for (int u=0; u<32; ++u) acc[u] += fc1w[u*60+t]*h6;
    }

    // ---- fc2: 32 -> 12 ----
    float o12[12];
    #pragma unroll
    for (int o=0;o<12;++o){
        float s = fc2b[o];
        #pragma unroll
        for (int u=0;u<32;++u) s += fc2w[o*32+u]*acc[u];
        o12[o]=s;
    }
    float* op = out + (size_t)b*12;
    *reinterpret_cast<float4*>(op)   = make_float4(o12[0],o12[1],o12[2], o12[3]);
    *reinterpret_cast<float4*>(op+4) = make_float4(o12[4],o12[5],o12[6], o12[7]);
    *reinterpret_cast<float4*>(op+8) = make_float4(o12[8],o12[9],o12[10],o12[11]);
}

extern "C" void kernel_launch(void* const* d_in, const int* in_sizes, int n_in,
                              void* d_out, int out_size, void* d_ws, size_t ws_size,
                              hipStream_t stream)
{
    const float* x    = (const float*)d_in[0];
    const float* w1i  = (const float*)d_in[1];
    const float* w1h  = (const float*)d_in[2];
    const float* b1   = (const float*)d_in[3];
    const float* w2i  = (const float*)d_in[4];
    const float* w2h  = (const float*)d_in[5];
    const float* b2   = (const float*)d_in[6];
    const float* w3i  = (const float*)d_in[7];
    const float* w3h  = (const float*)d_in[8];
    const float* b3   = (const float*)d_in[9];
    const float* w4i  = (const float*)d_in[10];
    const float* w4h  = (const float*)d_in[11];
    const float* b4   = (const float*)d_in[12];
    const float* w5i  = (const float*)d_in[13];
    const float* w5h  = (const float*)d_in[14];
    const float* b5   = (const float*)d_in[15];
    const float* w6i  = (const float*)d_in[16];
    const float* w6h  = (const float*)d_in[17];
    const float* b6   = (const float*)d_in[18];
    const float* fc1w = (const float*)d_in[19];
    const float* fc1b = (const float*)d_in[20];
    const float* fc2w = (const float*)d_in[21];
    const float* fc2b = (const float*)d_in[22];

    // 32768 batch elements, 1 thread each. block=64 (one wave) -> 512 blocks
    // spread over 256 CUs (2 waves/CU). 128-thread+ blocks would leave CUs idle.
    lstm_fused<<<dim3(512), dim3(64), 0, stream>>>(
        x, w1i,w1h,b1, w2i,w2h,b2, w3i,w3h,b3,
        w4i,w4h,b4, w5i,w5h,b5, w6i,w6h,b6,
        fc1w,fc1b, fc2w,fc2b, (float*)d_out);
}

// Round 3
// 1321.312 us; speedup vs baseline: 1.4700x; 1.4700x over previous
//
#include <hip/hip_runtime.h>
#include <cstddef>

#define TSEQ 48
#define TDEC 60

__device__ __forceinline__ float rcpf(float x){ return __builtin_amdgcn_rcpf(x); }
__device__ __forceinline__ float sigm(float x){ return rcpf(1.0f + __expf(-x)); }
__device__ __forceinline__ float tanhx(float x){ return 1.0f - 2.0f*rcpf(__expf(2.0f*x) + 1.0f); }

// One batch element per 64-lane wave. e1's 128 gate-rows: lane L computes rows
// {L, 64+L} (weights register-resident). e2's 32 rows: lane L computes row L&31.
// e3/d1/d2/d3 gate-rows spread across lanes with shfl_xor gathers; h broadcast
// from the valid lane. h1/h2 shared per step through a per-wave LDS buffer.
__global__ __launch_bounds__(256, 2)
void lstm_fused(const float* __restrict__ x,
                const float* __restrict__ w1i, const float* __restrict__ w1h, const float* __restrict__ b1,
                const float* __restrict__ w2i, const float* __restrict__ w2h, const float* __restrict__ b2,
                const float* __restrict__ w3i, const float* __restrict__ w3h, const float* __restrict__ b3,
                const float* __restrict__ w4i, const float* __restrict__ w4h, const float* __restrict__ b4,
                const float* __restrict__ w5i, const float* __restrict__ w5h, const float* __restrict__ b5,
                const float* __restrict__ w6i, const float* __restrict__ w6h, const float* __restrict__ b6,
                const float* __restrict__ fc1w, const float* __restrict__ fc1b,
                const float* __restrict__ fc2w, const float* __restrict__ fc2b,
                float* __restrict__ out)
{
    const int lane = threadIdx.x & 63;
    const int w    = threadIdx.x >> 6;          // wave id in block (0..3)
    const int elem = blockIdx.x * 4 + w;        // batch element

    // per-wave LDS scratch (no cross-wave sharing -> zero barriers)
    __shared__ float h1s[4][32];
    __shared__ float h2s[4][8];
    __shared__ float h6s[4][64];   // 60 used, padded for float4 epilogue reads
    __shared__ float accs[4][32];

    const float* xrow = x + (size_t)elem * (TSEQ*8);

    // ---------------- weight preload (one-time, register-resident) ----------
    const int rA = lane;        // e1 row A: i-row (lane<32) or f-row (lane>=32)
    const int rB = 64 + lane;   // e1 row B: g-row (lane<32) or o-row (lane>=32)
    float w1iA[8], w1iB[8], w1hA[32], w1hB[32];
    {
        const float4* p;
        p = (const float4*)(w1i + rA*8);
        float4 v0=p[0], v1=p[1];
        w1iA[0]=v0.x;w1iA[1]=v0.y;w1iA[2]=v0.z;w1iA[3]=v0.w;
        w1iA[4]=v1.x;w1iA[5]=v1.y;w1iA[6]=v1.z;w1iA[7]=v1.w;
        p = (const float4*)(w1i + rB*8);
        v0=p[0]; v1=p[1];
        w1iB[0]=v0.x;w1iB[1]=v0.y;w1iB[2]=v0.z;w1iB[3]=v0.w;
        w1iB[4]=v1.x;w1iB[5]=v1.y;w1iB[6]=v1.z;w1iB[7]=v1.w;
        p = (const float4*)(w1h + rA*32);
        #pragma unroll
        for (int q=0;q<8;++q){ float4 v=p[q]; w1hA[4*q]=v.x;w1hA[4*q+1]=v.y;w1hA[4*q+2]=v.z;w1hA[4*q+3]=v.w; }
        p = (const float4*)(w1h + rB*32);
        #pragma unroll
        for (int q=0;q<8;++q){ float4 v=p[q]; w1hB[4*q]=v.x;w1hB[4*q+1]=v.y;w1hB[4*q+2]=v.z;w1hB[4*q+3]=v.w; }
    }
    const float bA_ = b1[rA], bB_ = b1[rB];
    const bool half = (lane < 32);   // e1: row B is g-row (tanh) iff lane<32

    const int r2 = lane & 31;        // e2 row
    float w2i_[32], w2h_[8];
    {
        const float4* p = (const float4*)(w2i + r2*32);
        #pragma unroll
        for (int q=0;q<8;++q){ float4 v=p[q]; w2i_[4*q]=v.x;w2i_[4*q+1]=v.y;w2i_[4*q+2]=v.z;w2i_[4*q+3]=v.w; }
        p = (const float4*)(w2h + r2*8);
        float4 v0=p[0], v1=p[1];
        w2h_[0]=v0.x;w2h_[1]=v0.y;w2h_[2]=v0.z;w2h_[3]=v0.w;
        w2h_[4]=v1.x;w2h_[5]=v1.y;w2h_[6]=v1.z;w2h_[7]=v1.w;
    }
    const float b2_ = b2[r2];
    const bool tg2 = ((r2>>3)==2);   // rows 16..23 = g-rows

    const int r3 = lane & 3;         // e3 / d3 row
    float w3i_[8];
    {
        const float4* p = (const float4*)(w3i + r3*8);
        float4 v0=p[0], v1=p[1];
        w3i_[0]=v0.x;w3i_[1]=v0.y;w3i_[2]=v0.z;w3i_[3]=v0.w;
        w3i_[4]=v1.x;w3i_[5]=v1.y;w3i_[6]=v1.z;w3i_[7]=v1.w;
    }
    const float w3h_ = w3h[r3], b3_ = b3[r3];
    const bool tg3 = (r3==2);

    const int r8 = lane & 7;         // d1 / d2 row
    const float w4i_ = w4i[r8], w4h0 = w4h[r8*2], w4h1 = w4h[r8*2+1], b4_ = b4[r8];
    const float w5i0 = w5i[r8*2], w5i1 = w5i[r8*2+1], w5h0 = w5h[r8*2], w5h1 = w5h[r8*2+1], b5_ = b5[r8];
    const bool tg45 = ((r8>>1)==2); // rows 4,5 = g-rows
    const float w6i0 = w6i[r3*2], w6i1 = w6i[r3*2+1], w6h_ = w6h[r3], b6_ = b6[r3];
    // tg3 doubles for d3 (r3==2)

    // ---------------- state init -------------------------------------------
    float h1r[32];                    // broadcast copy of h1 (uniform in wave)
    #pragma unroll
    for (int k=0;k<32;++k) h1r[k]=0.f;
    float h2r[8];
    #pragma unroll
    for (int k=0;k<8;++k) h2r[k]=0.f;
    float c1=0.f, c2=0.f, c3=0.f, h3=0.f;
    float c4=0.f, h4a=0.f, h4b=0.f;
    float c5=0.f, h5a=0.f, h5b=0.f;
    float c6=0.f, h6=0.f;

    // ---------------- time loop --------------------------------------------
    for (int t=0; t<TDEC; ++t){
        float din;
        if (t < TSEQ){
            // x_t: uniform address across wave -> one 32B broadcast fetch
            const float4 xa = *reinterpret_cast<const float4*>(xrow + t*8);
            const float4 xb = *reinterpret_cast<const float4*>(xrow + t*8 + 4);
            const float xv[8] = {xa.x,xa.y,xa.z,xa.w,xb.x,xb.y,xb.z,xb.w};

            // ---- e1: 2 gate-rows per lane, 4-way split accumulators -------
            float aacc[4] = {bA_, 0.f, 0.f, 0.f};
            float bacc[4] = {bB_, 0.f, 0.f, 0.f};
            #pragma unroll
            for (int j=0;j<8;++j){
                aacc[j&3] += w1iA[j]*xv[j];
                bacc[j&3] += w1iB[j]*xv[j];
            }
            #pragma unroll
            for (int k=0;k<32;++k){
                aacc[k&3] += w1hA[k]*h1r[k];
                bacc[k&3] += w1hB[k]*h1r[k];
            }
            const float gA = (aacc[0]+aacc[1])+(aacc[2]+aacc[3]);
            const float gB = (bacc[0]+bacc[1])+(bacc[2]+bacc[3]);
            const float aA = sigm(gA);                       // i (lo) / f (hi)
            const float sB = sigm(half ? 2.f*gB : gB);
            const float aB = half ? 2.f*sB-1.f : sB;         // tanh(g) / sigm(o)
            const float pA = __shfl_xor(aA, 32);
            const float pB = __shfl_xor(aB, 32);
            const float iv = half ? aA : pA;
            const float fv = half ? pA : aA;
            const float gv = half ? aB : pB;
            const float ov = half ? pB : aB;
            c1 = fv*c1 + iv*gv;
            const float h1n = ov*tanhx(c1);
            if (lane < 32) h1s[w][lane] = h1n;
            #pragma unroll
            for (int q=0;q<8;++q){
                float4 v = *reinterpret_cast<float4*>(&h1s[w][4*q]);
                h1r[4*q]=v.x; h1r[4*q+1]=v.y; h1r[4*q+2]=v.z; h1r[4*q+3]=v.w;
            }

            // ---- e2: one gate-row per lane --------------------------------
            float q2[4] = {b2_, 0.f, 0.f, 0.f};
            #pragma unroll
            for (int k=0;k<32;++k) q2[k&3] += w2i_[k]*h1r[k];
            #pragma unroll
            for (int k=0;k<8;++k)  q2[k&3] += w2h_[k]*h2r[k];
            const float g2 = (q2[0]+q2[1])+(q2[2]+q2[3]);
            const float s2 = sigm(tg2 ? 2.f*g2 : g2);
            const float a2 = tg2 ? 2.f*s2-1.f : s2;
            const float f2 = __shfl_xor(a2, 8);
            const float gg2= __shfl_xor(a2, 16);
            const float o2 = __shfl_xor(a2, 24);
            c2 = f2*c2 + a2*gg2;                 // valid where r2<8
            const float h2n = o2*tanhx(c2);
            if (lane < 8) h2s[w][lane] = h2n;
            {
                float4 v0 = *reinterpret_cast<float4*>(&h2s[w][0]);
                float4 v1 = *reinterpret_cast<float4*>(&h2s[w][4]);
                h2r[0]=v0.x;h2r[1]=v0.y;h2r[2]=v0.z;h2r[3]=v0.w;
                h2r[4]=v1.x;h2r[5]=v1.y;h2r[6]=v1.z;h2r[7]=v1.w;
            }

            // ---- e3: 4 gate-rows on r3, h3 broadcast ----------------------
            float g3 = b3_ + w3h_*h3;
            #pragma unroll
            for (int j=0;j<8;++j) g3 += w3i_[j]*h2r[j];
            const float s3 = sigm(tg3 ? 2.f*g3 : g3);
            const float a3 = tg3 ? 2.f*s3-1.f : s3;
            const float e1x = __shfl_xor(a3, 1);
            const float e2x = __shfl_xor(a3, 2);
            const float e3x = __shfl_xor(a3, 3);
            c3 = e1x*c3 + a3*e2x;                // valid where r3==0
            const float h3loc = e3x*tanhx(c3);
            h3 = __shfl(h3loc, 0);               // broadcast valid value
            din = h3;
        } else {
            din = xrow[(t-12)*8 + 4];            // x[:, -12:, TRAFFIC_COL]
        }

        // ---- d1: 8 gate-rows on r8 ----------------------------------------
        {
            const float g = b4_ + w4i_*din + w4h0*h4a + w4h1*h4b;
            const float s = sigm(tg45 ? 2.f*g : g);
            const float a = tg45 ? 2.f*s-1.f : s;
            const float y2 = __shfl_xor(a, 2);
            const float y4 = __shfl_xor(a, 4);
            const float y6 = __shfl_xor(a, 6);
            c4 = y2*c4 + a*y4;                   // valid where r8<2
            const float hl = y6*tanhx(c4);
            h4a = __shfl(hl, 0);
            h4b = __shfl(hl, 1);
        }
        // ---- d2 -----------------------------------------------------------
        {
            const float g = b5_ + w5i0*h4a + w5i1*h4b + w5h0*h5a + w5h1*h5b;
            const float s = sigm(tg45 ? 2.f*g : g);
            const float a = tg45 ? 2.f*s-1.f : s;
            const float y2 = __shfl_xor(a, 2);
            const float y4 = __shfl_xor(a, 4);
            const float y6 = __shfl_xor(a, 6);
            c5 = y2*c5 + a*y4;
            const float hl = y6*tanhx(c5);
            h5a = __shfl(hl, 0);
            h5b = __shfl(hl, 1);
        }
        // ---- d3: 4 gate-rows on r3 ----------------------------------------
        {
            const float g = b6_ + w6i0*h5a + w6i1*h5b + w6h_*h6;
            const float s = sigm(tg3 ? 2.f*g : g);
            const float a = tg3 ? 2.f*s-1.f : s;
            const float z1 = __shfl_xor(a, 1);
            const float z2 = __shfl_xor(a, 2);
            const float z3 = __shfl_xor(a, 3);
            c6 = z1*c6 + a*z2;                   // valid where r3==0
            const float hl = z3*tanhx(c6);
            h6 = __shfl(hl, 0);
        }
        if (lane == 0) h6s[w][t] = h6;
    }

    // ---------------- epilogue: fc1 (60->32) then fc2 (32->12) -------------
    {
        float o1 = fc1b[r2];
        const float* fr = fc1w + r2*60;
        #pragma unroll
        for (int q=0;q<15;++q){
            float4 hv = *reinterpret_cast<float4*>(&h6s[w][4*q]);
            float4 wv = *reinterpret_cast<const float4*>(fr + 4*q);
            o1 += wv.x*hv.x + wv.y*hv.y + wv.z*hv.z + wv.w*hv.w;
        }
        if (lane < 32) accs[w][lane] = o1;
    }
    if (lane < 12){
        float o = fc2b[lane];
        const float* fr = fc2w + lane*32;
        #pragma unroll
        for (int q=0;q<8;++q){
            float4 av = *reinterpret_cast<float4*>(&accs[w][4*q]);
            float4 wv = *reinterpret_cast<const float4*>(fr + 4*q);
            o += wv.x*av.x + wv.y*av.y + wv.z*av.z + wv.w*av.w;
        }
        out[(size_t)elem*12 + lane] = o;
    }
}

extern "C" void kernel_launch(void* const* d_in, const int* in_sizes, int n_in,
                              void* d_out, int out_size, void* d_ws, size_t ws_size,
                              hipStream_t stream)
{
    const float* x    = (const float*)d_in[0];
    const float* w1i  = (const float*)d_in[1];
    const float* w1h  = (const float*)d_in[2];
    const float* b1   = (const float*)d_in[3];
    const float* w2i  = (const float*)d_in[4];
    const float* w2h  = (const float*)d_in[5];
    const float* b2   = (const float*)d_in[6];
    const float* w3i  = (const float*)d_in[7];
    const float* w3h  = (const float*)d_in[8];
    const float* b3   = (const float*)d_in[9];
    const float* w4i  = (const float*)d_in[10];
    const float* w4h  = (const float*)d_in[11];
    const float* b4   = (const float*)d_in[12];
    const float* w5i  = (const float*)d_in[13];
    const float* w5h  = (const float*)d_in[14];
    const float* b5   = (const float*)d_in[15];
    const float* w6i  = (const float*)d_in[16];
    const float* w6h  = (const float*)d_in[17];
    const float* b6   = (const float*)d_in[18];
    const float* fc1w = (const float*)d_in[19];
    const float* fc1b = (const float*)d_in[20];
    const float* fc2w = (const float*)d_in[21];
    const float* fc2b = (const float*)d_in[22];

    // one element per wave: 32768 waves, 4 waves (4 elements) per 256-thread block
    lstm_fused<<<dim3(32768/4), dim3(256), 0, stream>>>(
        x, w1i,w1h,b1, w2i,w2h,b2, w3i,w3h,b3,
        w4i,w4h,b4, w5i,w5h,b5, w6i,w6h,b6,
        fc1w,fc1b, fc2w,fc2b, (float*)d_out);
}